// Round 1
// baseline (585.533 us; speedup 1.0000x reference)
//
#include <hip/hip_runtime.h>
#include <hip/hip_bf16.h>

#define B_SZ   16384
#define IN_DIM 4096
#define H1D    128
#define H2D    64
#define LAT    32

typedef _Float16 half8 __attribute__((ext_vector_type(8)));
typedef _Float16 half4 __attribute__((ext_vector_type(4)));
typedef float float4v __attribute__((ext_vector_type(4)));

// ---- workspace layout (bytes) ----
// W1t fp16 [128][4096] : 0       .. 1048576
// W2t fp16 [64][128]   : 1048576 .. 1064960
// W3t fp16 [32][64]    : 1064960 .. 1069056
// Wdt fp16 [4096][32]  : 1069056 .. 1331200
// b3off fp32 [32]      : 1331200 .. 1331328
// q fp16 [16384][32]   : 1331328 .. 2379904
#define WS_W2T  1048576
#define WS_W3T  1064960
#define WS_WDT  1069056
#define WS_B3O  1331200
#define WS_Q    1331328

// -------- prepass: transpose + fp32->fp16 convert weights, fold qparams into b3 --------
__global__ __launch_bounds__(256) void prep_kernel(
    const float* __restrict__ W1, const float* __restrict__ W2,
    const float* __restrict__ W3, const float* __restrict__ Wd,
    const float* __restrict__ b3, const float* __restrict__ qp,
    _Float16* __restrict__ W1t, _Float16* __restrict__ W2t,
    _Float16* __restrict__ W3t, _Float16* __restrict__ Wdt,
    float* __restrict__ b3off)
{
    int t = blockIdx.x * 256 + threadIdx.x;
    if (t < IN_DIM * H1D) {              // W1[k][n] -> W1t[n][k]
        int k = t >> 7, n = t & 127;
        W1t[n * IN_DIM + k] = (_Float16)W1[t];
    }
    if (t < LAT * IN_DIM) {              // Wd[k][n] -> Wdt[n][k]
        int k = t >> 12, n = t & 4095;
        Wdt[n * LAT + k] = (_Float16)Wd[t];
    }
    if (t < H1D * H2D) {                 // W2[k][n] -> W2t[n][k]
        int k = t >> 6, n = t & 63;
        W2t[n * H1D + k] = (_Float16)W2[t];
    }
    if (t < H2D * LAT) {                 // W3[k][n] -> W3t[n][k]
        int k = t >> 5, n = t & 31;
        W3t[n * H2D + k] = (_Float16)W3[t];
    }
    if (t < LAT) {
        float s = b3[t];
        #pragma unroll
        for (int r = 0; r < 6; ++r) s += qp[r * LAT + t];
        b3off[t] = s;
    }
}

// -------- encoder: x[16384,4096] -> q[16384,32] (fp16), fused 3 layers + cos --------
// 256 blocks x 512 threads; each block handles 64 rows.
__global__ __launch_bounds__(512) void encoder_kernel(
    const float* __restrict__ x,
    const _Float16* __restrict__ W1t, const _Float16* __restrict__ W2t,
    const _Float16* __restrict__ W3t,
    const float* __restrict__ b1, const float* __restrict__ b2,
    const float* __restrict__ b3off, _Float16* __restrict__ qout)
{
    __shared__ alignas(16) char smem[27648];
    _Float16* xt  = (_Float16*)smem;             // [64][72]  (phase 1)
    _Float16* wt  = (_Float16*)(smem + 9216);    // [128][72] (phase 1)
    _Float16* h1s = (_Float16*)smem;             // [64][136] (phase 2)
    _Float16* h2s = (_Float16*)(smem + 17408);   // [64][72]  (phase 2)

    const int tid  = threadIdx.x;
    const int lane = tid & 63;
    const int w    = tid >> 6;        // 0..7
    const int l15  = lane & 15;
    const int quad = lane >> 4;       // 0..3
    const int rb0  = blockIdx.x * 64;

    // ---- layer 1: h1[64][128] = relu(x_tile @ W1 + b1), MFMA 16x16x32 ----
    const int wr = w >> 1;            // row group (16 rows)
    const int wc = w & 1;             // col group (64 cols)

    float4v acc[4];
    #pragma unroll
    for (int nt = 0; nt < 4; ++nt) {
        float bv = b1[wc * 64 + nt * 16 + l15];
        acc[nt] = (float4v){bv, bv, bv, bv};
    }

    for (int kit = 0; kit < IN_DIM / 64; ++kit) {
        // stage x tile [64][64] fp32 -> fp16 LDS (rows padded to 72)
        #pragma unroll
        for (int i = 0; i < 2; ++i) {
            int idx = tid + i * 512;             // 0..1023
            int r   = idx >> 4;                  // 0..63
            int c4  = idx & 15;                  // float4 index
            float4v xv = ((const float4v*)(x + (size_t)(rb0 + r) * IN_DIM + kit * 64))[c4];
            half4 p;
            p[0] = (_Float16)xv[0]; p[1] = (_Float16)xv[1];
            p[2] = (_Float16)xv[2]; p[3] = (_Float16)xv[3];
            *(half4*)(xt + r * 72 + c4 * 4) = p;
        }
        // stage W1t tile [128][64] fp16 (rows padded to 72)
        #pragma unroll
        for (int i = 0; i < 2; ++i) {
            int idx = tid + i * 512;             // 0..1023
            int n   = idx >> 3;                  // 0..127
            int c   = idx & 7;                   // uint4 index (8 halves)
            uint4 v = ((const uint4*)(W1t + (size_t)n * IN_DIM + kit * 64))[c];
            *(uint4*)(wt + n * 72 + c * 8) = v;
        }
        __syncthreads();
        #pragma unroll
        for (int ks = 0; ks < 2; ++ks) {
            half8 a = *(const half8*)(xt + (wr * 16 + l15) * 72 + ks * 32 + quad * 8);
            #pragma unroll
            for (int nt = 0; nt < 4; ++nt) {
                half8 b = *(const half8*)(wt + (wc * 64 + nt * 16 + l15) * 72 + ks * 32 + quad * 8);
                acc[nt] = __builtin_amdgcn_mfma_f32_16x16x32_f16(a, b, acc[nt], 0, 0, 0);
            }
        }
        __syncthreads();
    }

    // epilogue: relu -> h1s (rows padded to 136)
    #pragma unroll
    for (int nt = 0; nt < 4; ++nt) {
        int c = wc * 64 + nt * 16 + l15;
        #pragma unroll
        for (int r = 0; r < 4; ++r) {
            int row = wr * 16 + quad * 4 + r;
            float v = acc[nt][r];
            h1s[row * 136 + c] = (_Float16)(v > 0.f ? v : 0.f);
        }
    }
    __syncthreads();

    // ---- layer 2: h2[64][64] = relu(h1 @ W2 + b2) ----
    const int rb2 = (w & 3) * 16;
    const int wc2 = w >> 2;           // 0..1 (32 cols each)
    float4v acc2[2];
    #pragma unroll
    for (int nt = 0; nt < 2; ++nt) {
        float bv = b2[wc2 * 32 + nt * 16 + l15];
        acc2[nt] = (float4v){bv, bv, bv, bv};
    }
    #pragma unroll
    for (int ks = 0; ks < 4; ++ks) {
        half8 a = *(const half8*)(h1s + (rb2 + l15) * 136 + ks * 32 + quad * 8);
        #pragma unroll
        for (int nt = 0; nt < 2; ++nt) {
            int n = wc2 * 32 + nt * 16 + l15;
            half8 b = *(const half8*)(W2t + n * H1D + ks * 32 + quad * 8);
            acc2[nt] = __builtin_amdgcn_mfma_f32_16x16x32_f16(a, b, acc2[nt], 0, 0, 0);
        }
    }
    #pragma unroll
    for (int nt = 0; nt < 2; ++nt) {
        int c = wc2 * 32 + nt * 16 + l15;
        #pragma unroll
        for (int r = 0; r < 4; ++r) {
            int row = rb2 + quad * 4 + r;
            float v = acc2[nt][r];
            h2s[row * 72 + c] = (_Float16)(v > 0.f ? v : 0.f);
        }
    }
    __syncthreads();

    // ---- layer 3: z[64][32] = h2 @ W3 + (b3 + qparam offset); q = cos(z) ----
    const int rb3 = (w & 3) * 16;
    const int wc3 = w >> 2;           // 0..1 (16 cols each)
    int c3 = wc3 * 16 + l15;
    float bv3 = b3off[c3];
    float4v acc3 = (float4v){bv3, bv3, bv3, bv3};
    #pragma unroll
    for (int ks = 0; ks < 2; ++ks) {
        half8 a = *(const half8*)(h2s + (rb3 + l15) * 72 + ks * 32 + quad * 8);
        half8 b = *(const half8*)(W3t + c3 * H2D + ks * 32 + quad * 8);
        acc3 = __builtin_amdgcn_mfma_f32_16x16x32_f16(a, b, acc3, 0, 0, 0);
    }
    #pragma unroll
    for (int r = 0; r < 4; ++r) {
        int row = rb0 + rb3 + quad * 4 + r;
        qout[(size_t)row * LAT + c3] = (_Float16)cosf(acc3[r]);
    }
}

// -------- decoder: out[16384,4096] = q @ Wd + bd (fp32 out) --------
// 4096 blocks x 256 threads; block = 64 rows x 256 cols.
__global__ __launch_bounds__(256) void decoder_kernel(
    const _Float16* __restrict__ qin, const _Float16* __restrict__ Wdt,
    const float* __restrict__ bd, float* __restrict__ out)
{
    __shared__ alignas(16) _Float16 qs[64 * 40];   // rows padded to 40
    const int tid  = threadIdx.x;
    const int lane = tid & 63;
    const int w    = tid >> 6;        // 0..3
    const int l15  = lane & 15;
    const int quad = lane >> 4;
    const int rowBlk = blockIdx.x & 255;
    const int colBlk = blockIdx.x >> 8;     // 0..15
    const int rb = rowBlk * 64;
    const int cb = colBlk * 256 + w * 64;

    // stage q tile [64][32] fp16 -> LDS
    {
        int r = tid >> 2;             // 0..63
        int c = tid & 3;              // uint4 index (8 halves)
        uint4 v = *((const uint4*)(qin + (size_t)(rb + r) * LAT) + c);
        *(uint4*)(qs + r * 40 + c * 8) = v;
    }
    __syncthreads();

    half8 a[4];
    #pragma unroll
    for (int mt = 0; mt < 4; ++mt)
        a[mt] = *(const half8*)(qs + (mt * 16 + l15) * 40 + quad * 8);

    #pragma unroll
    for (int nt = 0; nt < 4; ++nt) {
        int c = cb + nt * 16 + l15;
        half8 b = *(const half8*)(Wdt + (size_t)c * LAT + quad * 8);
        float bv = bd[c];
        float4v bias = (float4v){bv, bv, bv, bv};
        #pragma unroll
        for (int mt = 0; mt < 4; ++mt) {
            float4v o = __builtin_amdgcn_mfma_f32_16x16x32_f16(a[mt], b, bias, 0, 0, 0);
            #pragma unroll
            for (int r = 0; r < 4; ++r) {
                out[(size_t)(rb + mt * 16 + quad * 4 + r) * IN_DIM + c] = o[r];
            }
        }
    }
}

extern "C" void kernel_launch(void* const* d_in, const int* in_sizes, int n_in,
                              void* d_out, int out_size, void* d_ws, size_t ws_size,
                              hipStream_t stream)
{
    const float* x  = (const float*)d_in[0];
    const float* W1 = (const float*)d_in[1];
    const float* b1 = (const float*)d_in[2];
    const float* W2 = (const float*)d_in[3];
    const float* b2 = (const float*)d_in[4];
    const float* W3 = (const float*)d_in[5];
    const float* b3 = (const float*)d_in[6];
    const float* qp = (const float*)d_in[7];
    const float* Wd = (const float*)d_in[8];
    const float* bd = (const float*)d_in[9];
    float* out = (float*)d_out;

    char* ws = (char*)d_ws;
    _Float16* W1t = (_Float16*)(ws);
    _Float16* W2t = (_Float16*)(ws + WS_W2T);
    _Float16* W3t = (_Float16*)(ws + WS_W3T);
    _Float16* Wdt = (_Float16*)(ws + WS_WDT);
    float*    b3o = (float*)(ws + WS_B3O);
    _Float16* qbuf= (_Float16*)(ws + WS_Q);

    prep_kernel<<<2048, 256, 0, stream>>>(W1, W2, W3, Wd, b3, qp, W1t, W2t, W3t, Wdt, b3o);
    encoder_kernel<<<256, 512, 0, stream>>>(x, W1t, W2t, W3t, b1, b2, b3o, qbuf);
    decoder_kernel<<<4096, 256, 0, stream>>>(qbuf, Wdt, bd, out);
}

// Round 2
// 519.343 us; speedup vs baseline: 1.1275x; 1.1275x over previous
//
#include <hip/hip_runtime.h>
#include <hip/hip_bf16.h>

#define B_SZ   16384
#define IN_DIM 4096
#define H1D    128
#define H2D    64
#define LAT    32

typedef _Float16 half8 __attribute__((ext_vector_type(8)));
typedef _Float16 half4 __attribute__((ext_vector_type(4)));
typedef float float4v __attribute__((ext_vector_type(4)));

// ---- workspace layout (bytes) ----
#define WS_W2T  1048576
#define WS_W3T  1064960
#define WS_WDT  1069056
#define WS_B3O  1331200
#define WS_Q    1331328

// -------- prepass: transpose + fp32->fp16 convert weights, fold qparams into b3 --------
__global__ __launch_bounds__(256) void prep_kernel(
    const float* __restrict__ W1, const float* __restrict__ W2,
    const float* __restrict__ W3, const float* __restrict__ Wd,
    const float* __restrict__ b3, const float* __restrict__ qp,
    _Float16* __restrict__ W1t, _Float16* __restrict__ W2t,
    _Float16* __restrict__ W3t, _Float16* __restrict__ Wdt,
    float* __restrict__ b3off)
{
    int t = blockIdx.x * 256 + threadIdx.x;
    if (t < IN_DIM * H1D) {              // W1[k][n] -> W1t[n][k]
        int k = t >> 7, n = t & 127;
        W1t[n * IN_DIM + k] = (_Float16)W1[t];
    }
    if (t < LAT * IN_DIM) {              // Wd[k][n] -> Wdt[n][k]
        int k = t >> 12, n = t & 4095;
        Wdt[n * LAT + k] = (_Float16)Wd[t];
    }
    if (t < H1D * H2D) {                 // W2[k][n] -> W2t[n][k]
        int k = t >> 6, n = t & 63;
        W2t[n * H1D + k] = (_Float16)W2[t];
    }
    if (t < H2D * LAT) {                 // W3[k][n] -> W3t[n][k]
        int k = t >> 5, n = t & 31;
        W3t[n * H2D + k] = (_Float16)W3[t];
    }
    if (t < LAT) {
        float s = b3[t];
        #pragma unroll
        for (int r = 0; r < 6; ++r) s += qp[r * LAT + t];
        b3off[t] = s;
    }
}

static __device__ __forceinline__ half8 cvt8(float4v v0, float4v v1) {
    half8 h;
    h[0] = (_Float16)v0[0]; h[1] = (_Float16)v0[1];
    h[2] = (_Float16)v0[2]; h[3] = (_Float16)v0[3];
    h[4] = (_Float16)v1[0]; h[5] = (_Float16)v1[1];
    h[6] = (_Float16)v1[2]; h[7] = (_Float16)v1[3];
    return h;
}

// -------- encoder: barrier-free K-loop, K-split across 4 waves --------
// 512 blocks x 256 threads; block = 32 rows of x; wave w owns K-quarter [w*1024, w*1024+1024)
__global__ __launch_bounds__(256, 2) void encoder_kernel(
    const float* __restrict__ x,
    const _Float16* __restrict__ W1t, const _Float16* __restrict__ W2t,
    const _Float16* __restrict__ W3t,
    const float* __restrict__ b1, const float* __restrict__ b2,
    const float* __restrict__ b3off, _Float16* __restrict__ qout)
{
    __shared__ alignas(16) float part[4 * 32 * 132];   // 67584 B, K-split partials
    __shared__ alignas(16) _Float16 h1s[32 * 136];     // 8704 B
    _Float16* h2s = (_Float16*)part;                   // [32][72], aliases part (dead by then)

    const int tid  = threadIdx.x;
    const int lane = tid & 63;
    const int w    = tid >> 6;        // 0..3  = K-quarter
    const int l15  = lane & 15;
    const int quad = lane >> 4;       // 0..3
    const int rb0  = blockIdx.x * 32;

    // ---- layer 1: acc[2 row-frags][8 col-frags], K-chunk = 1024 per wave ----
    float4v acc[2][8];
    #pragma unroll
    for (int mg = 0; mg < 2; ++mg)
        #pragma unroll
        for (int ct = 0; ct < 8; ++ct)
            acc[mg][ct] = (float4v){0.f, 0.f, 0.f, 0.f};

    const float* xp0 = x + (size_t)(rb0 + l15) * IN_DIM + w * 1024 + quad * 8;
    const float* xp1 = xp0 + 16 * IN_DIM;
    const _Float16* wp[8];
    #pragma unroll
    for (int ct = 0; ct < 8; ++ct)
        wp[ct] = W1t + (size_t)(ct * 16 + l15) * IN_DIM + w * 1024 + quad * 8;

    #pragma unroll 2
    for (int kk = 0; kk < 32; ++kk) {
        const int ko = kk * 32;
        float4v x00 = *(const float4v*)(xp0 + ko);
        float4v x01 = *(const float4v*)(xp0 + ko + 4);
        float4v x10 = *(const float4v*)(xp1 + ko);
        float4v x11 = *(const float4v*)(xp1 + ko + 4);
        half8 a0 = cvt8(x00, x01);
        half8 a1 = cvt8(x10, x11);
        #pragma unroll
        for (int ct = 0; ct < 8; ++ct) {
            half8 b = *(const half8*)(wp[ct] + ko);
            acc[0][ct] = __builtin_amdgcn_mfma_f32_16x16x32_f16(a0, b, acc[0][ct], 0, 0, 0);
            acc[1][ct] = __builtin_amdgcn_mfma_f32_16x16x32_f16(a1, b, acc[1][ct], 0, 0, 0);
        }
    }

    // write per-wave partials to LDS
    {
        float* pw = part + w * (32 * 132);
        #pragma unroll
        for (int mg = 0; mg < 2; ++mg)
            #pragma unroll
            for (int ct = 0; ct < 8; ++ct)
                #pragma unroll
                for (int r = 0; r < 4; ++r)
                    pw[(mg * 16 + quad * 4 + r) * 132 + ct * 16 + l15] = acc[mg][ct][r];
    }
    __syncthreads();

    // reduce 4 partials + bias + relu -> h1s fp16 [32][136]
    #pragma unroll
    for (int i = 0; i < 4; ++i) {
        int chunk = tid * 4 + i;          // 0..1023 float4 chunks of [32][128]
        int row = chunk >> 5;
        int c4  = chunk & 31;
        const float* p = part + row * 132 + c4 * 4;
        float4v s = *(const float4v*)(p)
                  + *(const float4v*)(p + 32 * 132)
                  + *(const float4v*)(p + 2 * 32 * 132)
                  + *(const float4v*)(p + 3 * 32 * 132);
        float4v bb = *(const float4v*)(b1 + c4 * 4);
        s = s + bb;
        half4 h;
        h[0] = (_Float16)(s[0] > 0.f ? s[0] : 0.f);
        h[1] = (_Float16)(s[1] > 0.f ? s[1] : 0.f);
        h[2] = (_Float16)(s[2] > 0.f ? s[2] : 0.f);
        h[3] = (_Float16)(s[3] > 0.f ? s[3] : 0.f);
        *(half4*)(h1s + row * 136 + c4 * 4) = h;
    }
    __syncthreads();

    // ---- layer 2: h2[32][64] = relu(h1 @ W2 + b2); wave w -> cols w*16..+15 ----
    {
        float bv2 = b2[w * 16 + l15];
        float4v a2[2] = {(float4v){bv2, bv2, bv2, bv2}, (float4v){bv2, bv2, bv2, bv2}};
        #pragma unroll
        for (int kk = 0; kk < 4; ++kk) {
            half8 b = *(const half8*)(W2t + (w * 16 + l15) * H1D + kk * 32 + quad * 8);
            half8 a0 = *(const half8*)(h1s + l15 * 136 + kk * 32 + quad * 8);
            half8 a1 = *(const half8*)(h1s + (16 + l15) * 136 + kk * 32 + quad * 8);
            a2[0] = __builtin_amdgcn_mfma_f32_16x16x32_f16(a0, b, a2[0], 0, 0, 0);
            a2[1] = __builtin_amdgcn_mfma_f32_16x16x32_f16(a1, b, a2[1], 0, 0, 0);
        }
        __syncthreads();   // h2s aliases part; ensure reduction reads are done
        #pragma unroll
        for (int mg = 0; mg < 2; ++mg)
            #pragma unroll
            for (int r = 0; r < 4; ++r) {
                float v = a2[mg][r];
                h2s[(mg * 16 + quad * 4 + r) * 72 + w * 16 + l15] = (_Float16)(v > 0.f ? v : 0.f);
            }
    }
    __syncthreads();

    // ---- layer 3 + cos: wave w -> row-group w>>1, col-group w&1 ----
    {
        const int mg3 = w >> 1;
        const int ct3 = w & 1;
        const int c3  = ct3 * 16 + l15;
        float bv3 = b3off[c3];
        float4v a3 = (float4v){bv3, bv3, bv3, bv3};
        #pragma unroll
        for (int kk = 0; kk < 2; ++kk) {
            half8 a = *(const half8*)(h2s + (mg3 * 16 + l15) * 72 + kk * 32 + quad * 8);
            half8 b = *(const half8*)(W3t + c3 * H2D + kk * 32 + quad * 8);
            a3 = __builtin_amdgcn_mfma_f32_16x16x32_f16(a, b, a3, 0, 0, 0);
        }
        #pragma unroll
        for (int r = 0; r < 4; ++r) {
            int row = rb0 + mg3 * 16 + quad * 4 + r;
            qout[(size_t)row * LAT + c3] = (_Float16)cosf(a3[r]);
        }
    }
}

// -------- decoder: out[16384,4096] = q @ Wd + bd, LDS-transposed dwordx4 stores --------
// 4096 blocks x 256 threads; block = 64 rows x 256 cols.
__global__ __launch_bounds__(256, 2) void decoder_kernel(
    const _Float16* __restrict__ qin, const _Float16* __restrict__ Wdt,
    const float* __restrict__ bd, float* __restrict__ out)
{
    __shared__ alignas(16) _Float16 qs[64 * 40];   // 5120 B
    __shared__ alignas(16) float ot[64 * 260];     // 66560 B
    const int tid  = threadIdx.x;
    const int lane = tid & 63;
    const int w    = tid >> 6;        // 0..3
    const int l15  = lane & 15;
    const int quad = lane >> 4;
    const int rowBlk = blockIdx.x >> 4;     // 0..255
    const int colBlk = blockIdx.x & 15;     // 0..15
    const int rb = rowBlk * 64;

    // stage q tile [64][32] fp16 -> LDS
    {
        int r = tid >> 2;
        int c = tid & 3;
        uint4 v = *((const uint4*)(qin + (size_t)(rb + r) * LAT) + c);
        *(uint4*)(qs + r * 40 + c * 8) = v;
    }
    __syncthreads();

    half8 a[4];
    #pragma unroll
    for (int mt = 0; mt < 4; ++mt)
        a[mt] = *(const half8*)(qs + (mt * 16 + l15) * 40 + quad * 8);

    #pragma unroll
    for (int nt = 0; nt < 4; ++nt) {
        int ccol = w * 64 + nt * 16 + l15;           // col within 256-wide tile
        int gcol = colBlk * 256 + ccol;
        half8 b = *(const half8*)(Wdt + (size_t)gcol * LAT + quad * 8);
        float bv = bd[gcol];
        float4v bias = (float4v){bv, bv, bv, bv};
        #pragma unroll
        for (int mt = 0; mt < 4; ++mt) {
            float4v o = __builtin_amdgcn_mfma_f32_16x16x32_f16(a[mt], b, bias, 0, 0, 0);
            #pragma unroll
            for (int r = 0; r < 4; ++r)
                ot[(mt * 16 + quad * 4 + r) * 260 + ccol] = o[r];
        }
    }
    __syncthreads();

    // vectorized store: wave per row, 1 KB contiguous per instruction
    {
        const int trow = tid >> 6;          // 0..3
        const int tcol = (tid & 63) * 4;    // 0..252
        #pragma unroll
        for (int r0 = 0; r0 < 64; r0 += 4) {
            int row = r0 + trow;
            float4v v = *(const float4v*)(ot + row * 260 + tcol);
            *(float4v*)(out + (size_t)(rb + row) * IN_DIM + colBlk * 256 + tcol) = v;
        }
    }
}

extern "C" void kernel_launch(void* const* d_in, const int* in_sizes, int n_in,
                              void* d_out, int out_size, void* d_ws, size_t ws_size,
                              hipStream_t stream)
{
    const float* x  = (const float*)d_in[0];
    const float* W1 = (const float*)d_in[1];
    const float* b1 = (const float*)d_in[2];
    const float* W2 = (const float*)d_in[3];
    const float* b2 = (const float*)d_in[4];
    const float* W3 = (const float*)d_in[5];
    const float* b3 = (const float*)d_in[6];
    const float* qp = (const float*)d_in[7];
    const float* Wd = (const float*)d_in[8];
    const float* bd = (const float*)d_in[9];
    float* out = (float*)d_out;

    char* ws = (char*)d_ws;
    _Float16* W1t = (_Float16*)(ws);
    _Float16* W2t = (_Float16*)(ws + WS_W2T);
    _Float16* W3t = (_Float16*)(ws + WS_W3T);
    _Float16* Wdt = (_Float16*)(ws + WS_WDT);
    float*    b3o = (float*)(ws + WS_B3O);
    _Float16* qbuf= (_Float16*)(ws + WS_Q);

    prep_kernel<<<2048, 256, 0, stream>>>(W1, W2, W3, Wd, b3, qp, W1t, W2t, W3t, Wdt, b3o);
    encoder_kernel<<<512, 256, 0, stream>>>(x, W1t, W2t, W3t, b1, b2, b3o, qbuf);
    decoder_kernel<<<4096, 256, 0, stream>>>(qbuf, Wdt, bd, out);
}